// Round 18
// baseline (85.593 us; speedup 1.0000x reference)
//
#include <hip/hip_runtime.h>
#include <stdint.h>

// Radius-graph edge list, B=4, N=2048, cutoff 5.0.
// Output [2, B*P] int32: compacted valid edges (ascending flat index), -1 pad.
//
// Round-23: TWO nodes, ZERO global atomics, NO memset.
//   Insight from r7-vs-r14 accounting: a graph node costs ~3-4 us (r14's K1
//   got ~5 us faster than r7 yet total moved only -0.75 because a memset
//   node was added). So kill nodes and shrink K2, keep validated kernels.
//   K1 fill_find (2624 blk): fill = r14 byte-identical (2048 x 32KB -1
//      chunks). Finder = r14 core, but emits fp = b*kP + pf (unique, <2^23)
//      into an LDS list; block end writes count[bid] (UNCONDITIONAL -> no
//      zeroing needed, re-poison-proof) + fps to a private global slice.
//   K2 place (576 blk, 1 per finder block): load 576 counts -> wave-scan
//      prefix -> bulk-compact all ~12.3K fps into LDS (fixed-stride copies,
//      no pointer-chase) -> for each own edge: rank = #{fp' < fp} via
//      64-lane strided LDS scan (stride 64 = 2 lanes/bank = conflict-free,
//      m136) -> decode (i,j) from fp (sqrt decode, ~21/block: cheap) ->
//      write out[rank], overwriting K1's -1 (r14-validated overwrite).
//      Unique fps -> unique ranks -> no W-W races. Uniform work: no
//      stragglers (r15 law). No atomics, no fences.
// Pinned lessons: r3 grid.sync 286us; r5 fence/nontemporal 233us; r6
// barrier-after-fill vmcnt trap; r8/r16 contended-atomic arrival-rate; r9
// decode-per-pair VALU; r10/r11 per-lane pointer-chase; r12/r13 1-wave
// finder stalls; r14 TLP wins; r15 straggler law; r17 inversion overhead.

namespace {
constexpr int kB = 4;
constexpr int kN = 2048;
constexpr int kP = kN * (kN - 1) / 2;              // 2096128
constexpr long long kTotal = (long long)kB * kP;   // 8384512
constexpr float kCut2 = 25.0f;                     // 5.0^2
constexpr int kTile = 256;
constexpr int kNT = kN / kTile;                    // 8 tiles per dim
constexpr int kTPairs = kNT * (kNT + 1) / 2;       // 36 (ti <= tj)
constexpr int kJS = 4;                             // j-slices per tile-pair
constexpr int kSliceJ = kTile / kJS;               // 64 candidates per block
constexpr int kNF = kB * kTPairs * kJS;            // 576 finder blocks
constexpr int kFillBlk = 2048;
constexpr int kGrid1 = kNF + kFillBlk;             // 2624
constexpr int kFillN4 = (int)(2 * kTotal / 4);     // 4192256 int4s
constexpr int kFillPerBlk = 2048;                  // int4s per fill block
constexpr int kCapF = 1024;  // fp slots per finder block (mean ~21, 48x)
constexpr int kMaxT = 14336; // K2 LDS fp capacity (56 KB; T ~ 12.3K fixed)
}  // namespace

// p in [0,P) -> (i,j), i<j, triu row-major (K2 edge decode, ~21/block).
__device__ __forceinline__ void decode_pair(int p, int& i, int& j) {
  float t = sqrtf((float)(16769025 - 8 * p));
  int ii = (int)((4095.0f - t) * 0.5f);
  ii = ii < 0 ? 0 : (ii > kN - 2 ? kN - 2 : ii);
  while (ii > 0 && (ii * (4095 - ii)) / 2 > p) --ii;
  while (ii < kN - 2 && ((ii + 1) * (4094 - ii)) / 2 <= p) ++ii;
  i = ii;
  j = ii + 1 + (p - (ii * (4095 - ii)) / 2);
}

// ---------------------------------------------------------------------------
// K1: blocks 0..575 = finder -> private fp lists; blocks 576.. = -1 fill.
// ---------------------------------------------------------------------------
__global__ __launch_bounds__(256) void fill_find_kernel(
    const float* __restrict__ x, uint32_t* __restrict__ count,
    uint32_t* __restrict__ fpbuf, int* __restrict__ out) {
  const int t = threadIdx.x;
  const int bid = blockIdx.x;

  if (bid >= kNF) {
    // Filler: contiguous 32 KB chunk of -1; stores issue from cycle 0,
    // nothing follows them (no barrier trap). r14 byte-identical.
    const int4 m1 = make_int4(-1, -1, -1, -1);
    int4* o = (int4*)out;
    const int base = (bid - kNF) * kFillPerBlk;
#pragma unroll
    for (int s = 0; s < 8; ++s) {
      const int idx = base + s * 256 + t;
      if (idx < kFillN4) o[idx] = m1;
    }
    return;
  }

  // ---- Finder: block = (batch b, tile-pair u (ti<=tj), j-slice js) ----
  __shared__ float4 sp[kSliceJ];   // 64 staged j-candidates
  __shared__ uint32_t lfp[kCapF];  // private fp list
  __shared__ uint32_t lcnt;

  const int b = bid / (kTPairs * kJS);
  const int rem = bid - b * (kTPairs * kJS);
  const int u = rem / kJS;
  const int js = rem - u * kJS;
  int ti = 0, rowlen = kNT, acc = 0;
  while (acc + rowlen <= u) { acc += rowlen; --rowlen; ++ti; }
  const int tj = ti + (u - acc);

  const float3* __restrict__ xb3 = (const float3*)(x + (size_t)b * kN * 3);
  const int jbase = tj * kTile + js * kSliceJ;  // first j of this slice
  if (t < kSliceJ) {
    const float3 pj = xb3[jbase + t];
    sp[t] = make_float4(pj.x, pj.y, pj.z, 0.0f);
  }
  if (t == 0) lcnt = 0;
  const int i = ti * kTile + t;
  const float3 pi = xb3[i];
  __syncthreads();

  const uint32_t Ci = (uint32_t)((i * (4095 - i)) >> 1);  // C(i)
  const uint32_t bfp = (uint32_t)b * (uint32_t)kP;        // batch fp base
  const bool diag = (ti == tj);       // block-uniform
  const int jrel0 = js * kSliceJ;     // j offset of slice start within tile

  // Emission: LDS-only (atomicAdd on LDS counter + LDS store). No global
  // atomics anywhere (r8/r16 lesson: contention ~ arrival rate per line).
  auto emit = [&](uint32_t m, int jb0) {
    do {
      const int k = __ffs(m) - 1;
      m &= m - 1;
      const int j = jbase + jb0 + k;
      const uint32_t fp = bfp + Ci + (uint32_t)(j - i - 1);
      const uint32_t slot = atomicAdd(&lcnt, 1u);
      if (slot < (uint32_t)kCapF) lfp[slot] = fp;
    } while (m);
  };

  // r14-validated hot loop: 64 candidates, batched by 8, mask-gated emit.
#pragma unroll
  for (int jb = 0; jb < kSliceJ; jb += 8) {
    uint32_t m = 0;
#pragma unroll
    for (int k = 0; k < 8; ++k) {
      const float4 c = sp[jb + k];
      const float dx = pi.x - c.x;
      const float dy = pi.y - c.y;
      const float dz = pi.z - c.z;
      const bool hit = (dx * dx + dy * dy + dz * dz <= kCut2) &&
                       (!diag || (jrel0 + jb + k) > t);
      m |= (uint32_t)hit << k;
    }
    if (m) emit(m, jb);
  }

  __syncthreads();
  uint32_t c = lcnt;
  if (c > (uint32_t)kCapF) c = (uint32_t)kCapF;
  for (uint32_t e = t; e < c; e += 256) fpbuf[(size_t)bid * kCapF + e] = lfp[e];
  if (t == 0) count[bid] = c;  // UNCONDITIONAL: no memset needed, ever.
}

// ---------------------------------------------------------------------------
// K2: 576 blocks. Compact all fps to LDS, rank own edges, write final pairs.
// ---------------------------------------------------------------------------
__global__ __launch_bounds__(256) void place_kernel(
    const uint32_t* __restrict__ count, const uint32_t* __restrict__ fpbuf,
    int* __restrict__ out) {
  const int t = threadIdx.x;
  const int wave = t >> 6, lane = t & 63;
  const int f = blockIdx.x;

  const uint32_t myc = count[f];
  if (myc == 0) return;  // block-uniform

  __shared__ uint32_t cnts[kNF];   // 2.3 KB
  __shared__ uint32_t pref[kNF];   // 2.3 KB (exclusive prefix)
  __shared__ uint32_t wred[4];
  __shared__ uint32_t fpl[kMaxT];  // 56 KB compacted fps
  __shared__ uint32_t Tsh;

  for (int idx = t; idx < kNF; idx += 256) cnts[idx] = count[idx];
  __syncthreads();

  // Exclusive prefix over 576 counts: thread t owns chunk [t*3, t*3+3).
  const int c0 = t * 3;
  uint32_t l0 = 0, l1 = 0, l2 = 0, s = 0;
  if (c0 + 0 < kNF) { l0 = cnts[c0 + 0]; s += l0; }
  if (c0 + 1 < kNF) { l1 = cnts[c0 + 1]; s += l1; }
  if (c0 + 2 < kNF) { l2 = cnts[c0 + 2]; s += l2; }
  uint32_t run = s;  // inclusive wave scan of per-thread sums
  for (int o = 1; o < 64; o <<= 1) {
    uint32_t u = __shfl_up(run, o, 64);
    if (lane >= o) run += u;
  }
  if (lane == 63) wred[wave] = run;
  __syncthreads();
  uint32_t wb = 0;
  for (int w = 0; w < wave; ++w) wb += wred[w];
  uint32_t excl = wb + run - s;
  if (c0 + 0 < kNF) { pref[c0 + 0] = excl; excl += l0; }
  if (c0 + 1 < kNF) { pref[c0 + 1] = excl; excl += l1; }
  if (c0 + 2 < kNF) { pref[c0 + 2] = excl; excl += l2; }
  if (t == 191) Tsh = excl;  // owner of chunks 573..575 -> grand total
  __syncthreads();
  uint32_t T = Tsh;  // ~12.3K (fixed input); safety clamp below
  if (T > (uint32_t)kMaxT) T = (uint32_t)kMaxT;

  // Bulk-compact: each thread copies its owned chunks' fps (fixed-stride
  // source, contiguous dest; independent loads -> pipelined, no chase).
#pragma unroll
  for (int q = 0; q < 3; ++q) {
    const int f2 = c0 + q;
    if (f2 < kNF) {
      const uint32_t cc = cnts[f2];
      const uint32_t bs = pref[f2];
      for (uint32_t k = 0; k < cc; ++k)
        if (bs + k < (uint32_t)kMaxT) fpl[bs + k] = fpbuf[(size_t)f2 * kCapF + k];
    }
  }
  __syncthreads();

  // Rank + place own edges: wave w handles edges e = w, w+4, ...
  for (uint32_t e = (uint32_t)wave; e < myc; e += 4) {
    const uint32_t fp = fpbuf[(size_t)f * kCapF + e];
    uint32_t r = 0;
    for (uint32_t idx = lane; idx < T; idx += 64)  // stride-64: conflict-free
      r += (fpl[idx] < fp) ? 1u : 0u;
    for (int o = 32; o > 0; o >>= 1) r += __shfl_xor(r, o, 64);
    if (lane == 0) {
      const int b = (int)(fp / (uint32_t)kP);  // magic-mul
      const int pf = (int)(fp - (uint32_t)b * (uint32_t)kP);
      int i, j;
      decode_pair(pf, i, j);
      out[r] = (b << 11) + i;
      out[(size_t)kTotal + r] = (b << 11) + j;
    }
  }
}

extern "C" void kernel_launch(void* const* d_in, const int* in_sizes, int n_in,
                              void* d_out, int out_size, void* d_ws, size_t ws_size,
                              hipStream_t stream) {
  const float* x = (const float*)d_in[0];
  int* out = (int*)d_out;
  uint32_t* count = (uint32_t*)d_ws;            // [576]
  uint32_t* fpbuf = count + kNF;                // [576 * 1024] = 2.3 MB

  hipLaunchKernelGGL(fill_find_kernel, dim3(kGrid1), dim3(256), 0, stream, x,
                     count, fpbuf, out);
  hipLaunchKernelGGL(place_kernel, dim3(kNF), dim3(256), 0, stream, count, fpbuf,
                     out);
}

// Round 19
// 31.636 us; speedup vs baseline: 2.7055x; 2.7055x over previous
//
#include <hip/hip_runtime.h>
#include <stdint.h>

// Radius-graph edge list, B=4, N=2048, cutoff 5.0.
// Output [2, B*P] int32: compacted valid edges (ascending flat index), -1 pad.
//
// Round-24: REVERT to r14 (31.7 us, measured best) byte-identical.
// Final structure:
//   memset node: zero counts[4096] (16 KB).
//   K1 fill_find (2624 blk x 256): blocks 0-575 = sliced tiled finder
//      (batch, tile-pair ti<=tj, j-slice of 64): thread owns i, tests 64
//      LDS-staged j's in batches of 8 with mask-gated emission (spread
//      global atomicAdd on counts[cb] + stash write). Blocks 576-2623 =
//      contiguous 32 KB -1 int4 fill chunks of the 67 MB output; finder
//      stalls hide under the write stream (TLP, r14's win).
//   K2 scatter (4096 blk x 256): early-exit if cnt==0; 16 KB L2-hot counts
//      prefix reduce; pf-rank order restore within count-block; exact
//      brute-force ballot fallback if cnt > kCap.
// Structural floor evidence (18 rounds): output writes 67 MB ~ 11 us
// irreducible; all K2/node-overhead attacks failed with counter-diagnosed
// mechanisms: r3 coop grid.sync 286us (L2 flush/XCD); r5 fence+nontemporal
// 233us (287 GB/s writes); r6 barrier-after-fill vmcnt drain +20us; r8/r16
// contended atomics ~ arrival rate per line; r15/r18 few-hot-block serial
// placement 78-100us; r17 dispatch inversion +8us; r9-r13: pair-test cost
// is index bookkeeping; TLP (not ILP) hides it.

namespace {
constexpr int kB = 4;
constexpr int kN = 2048;
constexpr int kP = kN * (kN - 1) / 2;              // 2096128
constexpr long long kTotal = (long long)kB * kP;   // 8384512
constexpr float kCut2 = 25.0f;                     // 5.0^2
constexpr int kCap = 128;                          // stash slots per count-blk
constexpr int kNCBlk = 4096;                       // count-blocks (2048 pairs)
constexpr int kTile = 256;
constexpr int kNT = kN / kTile;                    // 8 tiles per dim
constexpr int kTPairs = kNT * (kNT + 1) / 2;       // 36 (ti <= tj)
constexpr int kJS = 4;                             // j-slices per tile-pair
constexpr int kSliceJ = kTile / kJS;               // 64 candidates per block
constexpr int kNF = kB * kTPairs * kJS;            // 576 finder blocks
constexpr int kFillBlk = 2048;
constexpr int kGrid1 = kNF + kFillBlk;             // 2624
constexpr int kFillN4 = (int)(2 * kTotal / 4);     // 4192256 int4s
constexpr int kFillPerBlk = 2048;                  // int4s per fill block
}  // namespace

// p in [0,P) -> (i,j), i<j, triu row-major (scatter fallback path only).
__device__ __forceinline__ void decode_pair(int p, int& i, int& j) {
  float t = sqrtf((float)(16769025 - 8 * p));
  int ii = (int)((4095.0f - t) * 0.5f);
  ii = ii < 0 ? 0 : (ii > kN - 2 ? kN - 2 : ii);
  while (ii > 0 && (ii * (4095 - ii)) / 2 > p) --ii;
  while (ii < kN - 2 && ((ii + 1) * (4094 - ii)) / 2 <= p) ++ii;
  i = ii;
  j = ii + 1 + (p - (ii * (4095 - ii)) / 2);
}

__device__ __forceinline__ bool pair_test(const float* __restrict__ x, int b, int p,
                                          int& gi, int& gj) {
  int i, j;
  decode_pair(p, i, j);
  const float* xb = x + (size_t)b * kN * 3;
  float dx = xb[3 * i + 0] - xb[3 * j + 0];
  float dy = xb[3 * i + 1] - xb[3 * j + 1];
  float dz = xb[3 * i + 2] - xb[3 * j + 2];
  gi = b * kN + i;
  gj = b * kN + j;
  return dx * dx + dy * dy + dz * dz <= kCut2;
}

// ---------------------------------------------------------------------------
// K1: blocks 0..575 = sliced tiled finder; blocks 576.. = -1 fill stream.
// ---------------------------------------------------------------------------
__global__ __launch_bounds__(256) void fill_find_kernel(
    const float* __restrict__ x, uint32_t* __restrict__ counts,
    int2* __restrict__ stash, int* __restrict__ out) {
  const int t = threadIdx.x;
  const int bid = blockIdx.x;

  if (bid >= kNF) {
    // Filler: contiguous 32 KB chunk of -1; stores issue from cycle 0,
    // nothing follows them (no barrier trap).
    const int4 m1 = make_int4(-1, -1, -1, -1);
    int4* o = (int4*)out;
    const int base = (bid - kNF) * kFillPerBlk;
#pragma unroll
    for (int s = 0; s < 8; ++s) {
      const int idx = base + s * 256 + t;
      if (idx < kFillN4) o[idx] = m1;
    }
    return;
  }

  // ---- Finder: block = (batch b, tile-pair u (ti<=tj), j-slice js) ----
  __shared__ float4 sp[kSliceJ];  // 64 staged j-candidates

  const int b = bid / (kTPairs * kJS);
  const int rem = bid - b * (kTPairs * kJS);
  const int u = rem / kJS;
  const int js = rem - u * kJS;
  int ti = 0, rowlen = kNT, acc = 0;
  while (acc + rowlen <= u) { acc += rowlen; --rowlen; ++ti; }
  const int tj = ti + (u - acc);

  const float3* __restrict__ xb3 = (const float3*)(x + (size_t)b * kN * 3);
  const int jbase = tj * kTile + js * kSliceJ;  // first j of this slice
  if (t < kSliceJ) {
    const float3 pj = xb3[jbase + t];
    sp[t] = make_float4(pj.x, pj.y, pj.z, 0.0f);
  }
  const int i = ti * kTile + t;
  const float3 pi = xb3[i];
  __syncthreads();  // before any big stores; finder does none (no vmcnt trap)

  const int gib = b << 11;            // global point-index base of batch b
  const uint32_t Ci = (uint32_t)((i * (4095 - i)) >> 1);  // C(i)
  const int cbb = b << 10;            // count-block base of batch b
  const bool diag = (ti == tj);       // block-uniform
  const int jrel0 = js * kSliceJ;     // j - tj*kTile offset of slice start

  // Emission: rare (~21 edges/block). Atomic (vmcnt) doesn't drain LDS
  // prefetch (lgkmcnt); slot-return dependency is paid only on hits.
  auto emit = [&](uint32_t m, int jb0) {
    do {
      const int k = __ffs(m) - 1;
      m &= m - 1;
      const int j = jbase + jb0 + k;
      const uint32_t pf = Ci + (uint32_t)(j - i - 1);
      const int cb = cbb + (int)(pf >> 11);
      const uint32_t slot = atomicAdd(&counts[cb], 1u);
      if (slot < (uint32_t)kCap)
        stash[(size_t)cb * kCap + slot] = make_int2(gib + i, gib + j);
    } while (m);
  };

  // 64 candidates, batched by 8 with mask-gated emission. TLP (several
  // finder+fill waves/SIMD) hides LDS latency; no fragile reg prefetch.
#pragma unroll
  for (int jb = 0; jb < kSliceJ; jb += 8) {
    uint32_t m = 0;
#pragma unroll
    for (int k = 0; k < 8; ++k) {
      const float4 c = sp[jb + k];
      const float dx = pi.x - c.x;
      const float dy = pi.y - c.y;
      const float dz = pi.z - c.z;
      const bool hit = (dx * dx + dy * dy + dz * dz <= kCut2) &&
                       (!diag || (jrel0 + jb + k) > t);
      m |= (uint32_t)hit << k;
    }
    if (m) emit(m, jb);
  }
}

// ---------------------------------------------------------------------------
// K2: scatter. Early-exit; prefix from 16 KB counts; pf-rank restores order;
// exact brute-force fallback if cnt > kCap.
// ---------------------------------------------------------------------------
__global__ __launch_bounds__(256) void scatter_kernel(
    const float* __restrict__ x, const uint32_t* __restrict__ counts,
    const int2* __restrict__ stash, int* __restrict__ out) {
  const int bid = blockIdx.x;
  const int t = threadIdx.x;

  const uint32_t cnt = counts[bid];
  if (cnt == 0) return;

  const uint4* c4 = (const uint4*)counts;  // exactly 4096 entries
  uint32_t part = 0;
#pragma unroll
  for (int q = 0; q < 4; ++q) {
    uint4 v = c4[t * 4 + q];
    int i0 = t * 16 + q * 4;
    part += (i0 + 0 < bid) ? v.x : 0u;
    part += (i0 + 1 < bid) ? v.y : 0u;
    part += (i0 + 2 < bid) ? v.z : 0u;
    part += (i0 + 3 < bid) ? v.w : 0u;
  }
  for (int o = 32; o > 0; o >>= 1) part += __shfl_down(part, o, 64);
  __shared__ uint32_t wred[4];
  if ((t & 63) == 0) wred[t >> 6] = part;
  __syncthreads();
  if (t == 0) wred[0] = wred[0] + wred[1] + wred[2] + wred[3];
  __syncthreads();
  const uint32_t off = wred[0];

  if (cnt <= (uint32_t)kCap) {
    __shared__ int2 ebuf[kCap];
    __shared__ uint32_t pfb[kCap];
    for (uint32_t e = t; e < cnt; e += 256) {
      int2 v = stash[(size_t)bid * kCap + e];
      ebuf[e] = v;
      int i = v.x & 2047, j = v.y & 2047;
      pfb[e] = (uint32_t)((i * (4095 - i)) / 2 + (j - i - 1));
    }
    __syncthreads();
    for (uint32_t e = t; e < cnt; e += 256) {
      uint32_t mypf = pfb[e];
      uint32_t rank = 0;
      for (uint32_t f = 0; f < cnt; ++f) rank += (pfb[f] < mypf) ? 1u : 0u;
      out[off + rank] = ebuf[e].x;
      out[(size_t)kTotal + off + rank] = ebuf[e].y;
    }
    return;
  }

  // Fallback (cnt > kCap): exact ballot recompute of this count-block's
  // 2048-pair range.
  const int wave = t >> 6, lane = t & 63;
  const int b = bid >> 10;
  const int p0 = (bid & 1023) << 11;
  __shared__ uint32_t slot[32];
  unsigned long long masks[8];
  int gi[8], gj[8];
  bool fl[8];
#pragma unroll
  for (int k = 0; k < 8; ++k) {
    int p = p0 + k * 256 + t;
    fl[k] = (p < kP) && pair_test(x, b, p, gi[k], gj[k]);
    masks[k] = __ballot(fl[k]);
    if (lane == 0) slot[k * 4 + wave] = (uint32_t)__popcll(masks[k]);
  }
  __syncthreads();
  if (t == 0) {
    uint32_t run = 0;
    for (int s = 0; s < 32; ++s) {
      uint32_t c = slot[s];
      slot[s] = run;
      run += c;
    }
  }
  __syncthreads();
#pragma unroll
  for (int k = 0; k < 8; ++k) {
    if (fl[k]) {
      uint32_t pos = off + slot[k * 4 + wave] +
                     (uint32_t)__popcll(masks[k] & ((1ULL << lane) - 1ULL));
      out[pos] = gi[k];
      out[(size_t)kTotal + pos] = gj[k];
    }
  }
}

extern "C" void kernel_launch(void* const* d_in, const int* in_sizes, int n_in,
                              void* d_out, int out_size, void* d_ws, size_t ws_size,
                              hipStream_t stream) {
  const float* x = (const float*)d_in[0];
  int* out = (int*)d_out;
  uint32_t* counts = (uint32_t*)d_ws;           // [4096]
  int2* stash = (int2*)(counts + 4096);         // [4096 * 128] = 4 MB

  (void)hipMemsetAsync(counts, 0, kNCBlk * sizeof(uint32_t), stream);
  hipLaunchKernelGGL(fill_find_kernel, dim3(kGrid1), dim3(256), 0, stream, x,
                     counts, stash, out);
  hipLaunchKernelGGL(scatter_kernel, dim3(kNCBlk), dim3(256), 0, stream, x, counts,
                     stash, out);
}